// Round 3
// baseline (253.545 us; speedup 1.0000x reference)
//
#include <hip/hip_runtime.h>

// RWKV-7 DPLR single-step decode: B=64, H=32, K=V=128, fp32.
// Per (b,h): s = a^T H0 ; t = (q*g)^T H0 ; alpha=q.b ; beta=q.k
//            o = t + alpha*s + beta*v ; Ht = diag(g)H0 + b s^T + k v^T
//
// Round-3 structure: NO barriers, NO LDS. One wave per (b,h, 16-col slice);
// lane = (cl = lane&3 -> 4 cols, rg = lane>>2 -> 8 rows). H slice held as
// 8 x float4 in registers for the wave's whole straight-line lifetime.
// All reductions (s, t, alpha, beta) are 4-stage shfl_xor butterflies over
// the rg bits (masks 4,8,16,32). 4 independent waves per 256-thread block.

#define KD 128
#define VD 128
#define BH_TOTAL 2048   // B*H

__global__ __launch_bounds__(256, 4) void dplr_decode_t1_kernel(
    const float* __restrict__ q_,  const float* __restrict__ k_,
    const float* __restrict__ v_,  const float* __restrict__ a_,
    const float* __restrict__ b_,  const float* __restrict__ gk_,
    const float* __restrict__ h0_, float* __restrict__ out_)
{
    const int lane  = threadIdx.x & 63;
    const int wid   = threadIdx.x >> 6;            // wave in block, 0..3
    const int gw    = blockIdx.x * 4 + wid;        // global wave, 0..16383
    const int bh    = gw >> 3;                     // 0..2047
    const int slice = gw & 7;                      // 16-col slice, 0..7
    const int cl    = lane & 3;                    // col group in slice
    const int rg    = lane >> 2;                   // row group, 0..15
    const int r0    = rg * 8;                      // row base
    const int col   = slice * 16 + cl * 4;         // global col base

    const size_t vec_off = (size_t)bh * KD;
    const size_t h_off   = (size_t)bh * (KD * VD);

    // ---- H slice: 8 rows x 4 cols in registers ----
    const float* hp = h0_ + h_off + (size_t)r0 * VD + col;
    float4 H0r[8];
#pragma unroll
    for (int j = 0; j < 8; ++j)
        H0r[j] = *(const float4*)(hp + (size_t)j * VD);

    // ---- per-lane vector pieces ----
    const float4 v4  = *(const float4*)(v_  + vec_off + col);      // my 4 cols of v
    const float4 qA  = *(const float4*)(q_  + vec_off + r0);       // my 8 rows of q,gk,a,k,b
    const float4 qB  = *(const float4*)(q_  + vec_off + r0 + 4);
    const float4 gA  = *(const float4*)(gk_ + vec_off + r0);
    const float4 gB  = *(const float4*)(gk_ + vec_off + r0 + 4);
    const float4 aA  = *(const float4*)(a_  + vec_off + r0);
    const float4 aB  = *(const float4*)(a_  + vec_off + r0 + 4);
    const float4 kA  = *(const float4*)(k_  + vec_off + r0);
    const float4 kB  = *(const float4*)(k_  + vec_off + r0 + 4);
    const float4 bA  = *(const float4*)(b_  + vec_off + r0);
    const float4 bB  = *(const float4*)(b_  + vec_off + r0 + 4);

    const float qv[8] = {qA.x, qA.y, qA.z, qA.w, qB.x, qB.y, qB.z, qB.w};
    const float gkv[8]= {gA.x, gA.y, gA.z, gA.w, gB.x, gB.y, gB.z, gB.w};
    const float av[8] = {aA.x, aA.y, aA.z, aA.w, aB.x, aB.y, aB.z, aB.w};
    const float kv[8] = {kA.x, kA.y, kA.z, kA.w, kB.x, kB.y, kB.z, kB.w};
    const float bv[8] = {bA.x, bA.y, bA.z, bA.w, bB.x, bB.y, bB.z, bB.w};

    float g[8], qg[8];
#pragma unroll
    for (int j = 0; j < 8; ++j) { g[j] = __expf(gkv[j]); qg[j] = qv[j] * g[j]; }

    // ---- per-lane partials over my 8 rows ----
    float4 sp = make_float4(0.f, 0.f, 0.f, 0.f);   // a^T H  (my 4 cols)
    float4 tp = make_float4(0.f, 0.f, 0.f, 0.f);   // (qg)^T H
    float pab = 0.f, pqk = 0.f;                    // q.b, q.k partials
#pragma unroll
    for (int j = 0; j < 8; ++j) {
        const float4 h = H0r[j];
        sp.x += av[j] * h.x; sp.y += av[j] * h.y;
        sp.z += av[j] * h.z; sp.w += av[j] * h.w;
        tp.x += qg[j] * h.x; tp.y += qg[j] * h.y;
        tp.z += qg[j] * h.z; tp.w += qg[j] * h.w;
        pab  += qv[j] * bv[j];
        pqk  += qv[j] * kv[j];
    }

    // ---- butterfly over the 16 row-groups (same cl -> same columns) ----
    // Note: lanes 0..3 (cl=0..3) duplicate rows identically across cl, so
    // pab/pqk also reduce to the full 128-row dot products.
#pragma unroll
    for (int m = 4; m <= 32; m <<= 1) {
        sp.x += __shfl_xor(sp.x, m, 64); sp.y += __shfl_xor(sp.y, m, 64);
        sp.z += __shfl_xor(sp.z, m, 64); sp.w += __shfl_xor(sp.w, m, 64);
        tp.x += __shfl_xor(tp.x, m, 64); tp.y += __shfl_xor(tp.y, m, 64);
        tp.z += __shfl_xor(tp.z, m, 64); tp.w += __shfl_xor(tp.w, m, 64);
        pab  += __shfl_xor(pab,  m, 64);
        pqk  += __shfl_xor(pqk,  m, 64);
    }

    // ---- o = t + alpha*s + beta*v  (one row-group writes) ----
    if (rg == 0) {
        float4 o4;
        o4.x = tp.x + pab * sp.x + pqk * v4.x;
        o4.y = tp.y + pab * sp.y + pqk * v4.y;
        o4.z = tp.z + pab * sp.z + pqk * v4.z;
        o4.w = tp.w + pab * sp.w + pqk * v4.w;
        *(float4*)(out_ + (size_t)bh * VD + col) = o4;
    }

    // ---- Ht = g*H + b s^T + k v^T, straight from registers ----
    float* op = out_ + (size_t)BH_TOTAL * VD + h_off + (size_t)r0 * VD + col;
#pragma unroll
    for (int j = 0; j < 8; ++j) {
        const float4 h = H0r[j];
        float4 w;
        w.x = g[j] * h.x + bv[j] * sp.x + kv[j] * v4.x;
        w.y = g[j] * h.y + bv[j] * sp.y + kv[j] * v4.y;
        w.z = g[j] * h.z + bv[j] * sp.z + kv[j] * v4.z;
        w.w = g[j] * h.w + bv[j] * sp.w + kv[j] * v4.w;
        *(float4*)(op + (size_t)j * VD) = w;
    }
}

extern "C" void kernel_launch(void* const* d_in, const int* in_sizes, int n_in,
                              void* d_out, int out_size, void* d_ws, size_t ws_size,
                              hipStream_t stream) {
    const float* q  = (const float*)d_in[0];
    const float* k  = (const float*)d_in[1];
    const float* v  = (const float*)d_in[2];
    const float* a  = (const float*)d_in[3];
    const float* b  = (const float*)d_in[4];
    const float* gk = (const float*)d_in[5];
    const float* h0 = (const float*)d_in[6];
    float* out = (float*)d_out;

    // 16384 waves = 2048 (b,h) x 8 col-slices; 4 independent waves per block.
    dplr_decode_t1_kernel<<<BH_TOTAL * 8 / 4, 256, 0, stream>>>(q, k, v, a, b, gk, h0, out);
}